// Round 9
// baseline (178.111 us; speedup 1.0000x reference)
//
#include <hip/hip_runtime.h>

// Modulated deformable conv, fp32 in/out. B=4, CIN=COUT=256, H=W=64, KS=3, PAD=1.
// R9: fast scatter k_pre (coalesced reads), xpair-packed bf16 gathers (1x4B load
// per corner pair), M=64 rows/block (grid 256), quarter-tap dbuf slabs, 4 blk/CU.
// ws: [xpair: 4,194,304 uint = 16 MB][wfrag: 663,552 shorts = 1.33 MB] if it fits,
// else wfrag only (fp32 pairf-gather fallback).

#define WOFF_FRAG_OFF 589824
typedef unsigned short ushort_t;
typedef unsigned int   uint_t;

using short8 = __attribute__((ext_vector_type(8))) short;
using f32x4  = __attribute__((ext_vector_type(4))) float;

struct __attribute__((packed, aligned(4))) pairf { float x, y; };

__device__ inline ushort_t f2bf(float v) {
    unsigned u = __float_as_uint(v);
    unsigned r = u + 0x7fffu + ((u >> 16) & 1u);   // RNE (inputs finite)
    return (ushort_t)(r >> 16);
}

// ---- k_pre: [0, XB) blocks build xpair; [XB, XB+2592) scatter-swizzle weights ----
__global__ __launch_bounds__(256) void k_pre(
    const float* __restrict__ x,
    const float* __restrict__ w_conv,
    const float* __restrict__ w_off,
    ushort_t* __restrict__ wfrag,
    uint_t* __restrict__ xpair,
    int XB)
{
    const int bid = blockIdx.x;
    if (bid < XB) {
        // xpair[i] = (bf16(x[i]), bf16(x[i+1])); 8 elements per thread, coalesced.
        const int gid = bid * 256 + threadIdx.x;
        const size_t base = (size_t)gid << 3;
        const float4 f0 = *(const float4*)(x + base);
        const float4 f1 = *(const float4*)(x + base + 4);
        const float nxt = (base + 8 < 4194304u) ? x[base + 8] : 0.f;
        const float e[9] = {f0.x, f0.y, f0.z, f0.w, f1.x, f1.y, f1.z, f1.w, nxt};
        uint_t o[8];
#pragma unroll
        for (int k = 0; k < 8; ++k)
            o[k] = (uint_t)f2bf(e[k]) | ((uint_t)f2bf(e[k + 1]) << 16);
        *(uint4*)(xpair + base)     = make_uint4(o[0], o[1], o[2], o[3]);
        *(uint4*)(xpair + base + 4) = make_uint4(o[4], o[5], o[6], o[7]);
        return;
    }
    const int i = (bid - XB) * 256 + threadIdx.x;   // 0..663,551
    if (i < 589824) {
        // coalesced read of w_conv[t]; scatter 2B store into fragment order
        const int n = i / 2304;
        const int k_orig = i - n * 2304;
        const int cin = k_orig / 9;
        const int tap = k_orig - cin * 9;
        const int k_new = tap * 256 + cin;          // tap-outer
        const int kt = k_new >> 5, m = k_new & 31;
        const int lane = ((m >> 3) << 4) | (n & 15);
        wfrag[(((kt << 4) + (n >> 4)) * 64 + lane) * 8 + (m & 7)] = f2bf(w_conv[i]);
    } else if (i < 652032) {
        const int s = i - 589824;                    // w_off: 27 x 2304
        const int n = s / 2304;
        const int k_orig = s - n * 2304;
        const int cin = k_orig / 9;
        const int tap = k_orig - cin * 9;
        const int k_new = tap * 256 + cin;
        const int kt = k_new >> 5, m = k_new & 31;
        const int lane = ((m >> 3) << 4) | (n & 15);
        wfrag[WOFF_FRAG_OFF + ((kt * 2 + (n >> 4)) * 64 + lane) * 8 + (m & 7)] =
            f2bf(w_off[s]);
    } else {
        const int p = i - 652032;                    // zero-pad n=27..31: 72kt x 160
        const int kt = p / 160;
        const int rem = p - kt * 160;
        const int j = rem & 7, li = rem >> 3;        // li 0..19
        const int g = li / 5, l = 11 + (li - g * 5);
        wfrag[WOFF_FRAG_OFF + ((kt * 2 + 1) * 64 + (g << 4) + l) * 8 + j] = 0;
    }
}

// ---- k_all: one block per output row (b,h). 512 thr = 8 waves. ----
template<bool USE_PAIR>
__global__ __launch_bounds__(512, 4) void k_all(
    const float* __restrict__ x,
    const uint_t* __restrict__ xpair,
    const float* __restrict__ b_off,
    const ushort_t* __restrict__ wfrag,
    float* __restrict__ out)
{
    __shared__ short As[2][64 * 72];                 // 18,432 B; om_s aliases As[0]
    __shared__ __align__(16) float4 pwt[9 * 64];
    __shared__ __align__(16) int2   pidx[9 * 64];
    float* om_s = (float*)&As[0][0];                 // 32c x 64px fp32 = 8 KB

    const int bid = blockIdx.x;
    const int sid = ((bid & 7) << 5) | (bid >> 3);   // XCD-contiguous row bands
    const int b = sid >> 6, h = sid & 63;
    const int tid  = threadIdx.x;
    const int lane = tid & 63;
    const int wv   = tid >> 6;                        // 0..7
    const int quad = lane >> 4;
    const int px_s = tid & 63;                        // staging pixel
    const int ci0  = (tid >> 6) << 3;                 // staging cins: ci0..ci0+7

    const float*  xb = x + ((size_t)b << 20);
    const uint_t* xq = USE_PAIR ? xpair + ((size_t)b << 20) : nullptr;
    const ushort_t* woffb = wfrag + WOFF_FRAG_OFF;

    // ---------- phase 1: offset conv via MFMA, quarter-tap dbuf ----------
    const int m_w = wv & 3, nt_w = wv >> 2;           // wave's (m-tile, n-tile)
    f32x4 om_acc = {0.f, 0.f, 0.f, 0.f};

    auto stage1 = [&](int q, int bufi) {
        const int tap = q >> 2, cbase = (q & 3) << 6;
        const int ky = (tap * 11) >> 5, kx = tap - ky * 3;
        const int yy = h + ky - 1;
        const int xx = px_s + kx - 1;
        const bool v = ((unsigned)yy < 64u) & ((unsigned)xx < 64u);
        const int idx = v ? (yy << 6) + xx : 0;
        const float* p = xb + ((size_t)(cbase + ci0) << 12) + idx;
        uint_t o[4];
#pragma unroll
        for (int k = 0; k < 4; ++k) {
            float t0 = p[(size_t)(2 * k) << 12];
            float t1 = p[(size_t)(2 * k + 1) << 12];
            t0 = v ? t0 : 0.f;  t1 = v ? t1 : 0.f;
            o[k] = (uint_t)f2bf(t0) | ((uint_t)f2bf(t1) << 16);
        }
        *(uint4*)&As[bufi][px_s * 72 + ci0] = make_uint4(o[0], o[1], o[2], o[3]);
    };

    stage1(0, 0);
    __syncthreads();
    for (int q = 0; q < 36; ++q) {
        if (q < 35) stage1(q + 1, (q + 1) & 1);
        const short* cur = &As[q & 1][0];
#pragma unroll
        for (int k2 = 0; k2 < 2; ++k2) {
            const int ktg = q * 2 + k2;
            const short8 a = *(const short8*)&cur[((m_w << 4) + (lane & 15)) * 72 + k2 * 32 + quad * 8];
            const short8 bf = *(const short8*)(woffb + ((size_t)(ktg * 2 + nt_w) * 64 + lane) * 8);
            om_acc = __builtin_amdgcn_mfma_f32_16x16x32_bf16(a, bf, om_acc, 0, 0, 0);
        }
        __syncthreads();
    }
    {   // C/D: row = quad*4+reg -> px = m_w*16+quad*4+reg; col = lane&15 -> c
        const int c = (nt_w << 4) + (lane & 15);
        *(f32x4*)&om_s[c * 64 + (m_w << 4) + (quad << 2)] = om_acc;
    }
    __syncthreads();

    // ---------- phase 2: per-(tap,px) pair-gather params ----------
    for (int i2 = tid; i2 < 576; i2 += 512) {
        const int p2 = i2 & 63, tap = i2 >> 6;
        const int ky = (tap * 11) >> 5, kx = tap - ky * 3;
        const float dyv = om_s[(2 * tap) * 64 + p2] + b_off[2 * tap];
        const float dxv = om_s[(2 * tap + 1) * 64 + p2] + b_off[2 * tap + 1];
        const float mo  = om_s[(18 + tap) * 64 + p2] + b_off[18 + tap];
        const float mv  = 1.f / (1.f + expf(-mo));
        const float py  = dyv + (float)(h - 1 + ky);
        const float pxf = dxv + (float)(p2 - 1 + kx);
        const float y0f = floorf(py), x0f = floorf(pxf);
        const float wy = py - y0f,    wx = pxf - x0f;
        const float vy0 = (y0f >=  0.f && y0f <= 63.f) ? 1.f : 0.f;
        const float vy1 = (y0f >= -1.f && y0f <= 62.f) ? 1.f : 0.f;
        const int ry0 = (int)fminf(fmaxf(y0f, 0.f), 63.f);
        const int ry1 = (int)fminf(fmaxf(y0f + 1.f, 0.f), 63.f);
        const float rw0 = (1.f - wy) * vy0 * mv;
        const float rw1 = wy * vy1 * mv;
        const bool in01 = (x0f >= 0.f && x0f <= 62.f);
        const float wa = in01 ? (1.f - wx) : ((x0f == -1.f) ? wx : 0.f);
        const float wb = in01 ? wx : ((x0f == 63.f) ? (1.f - wx) : 0.f);
        const int bx = (int)fminf(fmaxf(x0f, 0.f), 62.f);
        pwt[i2]  = make_float4(wa, wb, rw0, rw1);
        pidx[i2] = make_int2(ry0 * 64 + bx, ry1 * 64 + bx);
    }
    __syncthreads();

    // ---------- phase 3: deformable sampling + main GEMM ----------
    f32x4 acc[4][2];
#pragma unroll
    for (int m = 0; m < 4; ++m)
#pragma unroll
        for (int nn = 0; nn < 2; ++nn) acc[m][nn] = f32x4{0.f, 0.f, 0.f, 0.f};

    const int nt_base = wv << 1;                      // wave's couts: wv*32..+31

    auto stage3 = [&](int q, int bufi) {
        const int tap = q >> 2, cbase = (q & 3) << 6;
        const float4 wt = pwt[tap * 64 + px_s];
        const int2   ii = pidx[tap * 64 + px_s];
        uint_t o[4];
        if (USE_PAIR) {
            const uint_t* q0 = xq + ((size_t)(cbase + ci0) << 12) + ii.x;
            const uint_t* q1 = xq + ((size_t)(cbase + ci0) << 12) + ii.y;
#pragma unroll
            for (int k = 0; k < 4; ++k) {
                ushort_t sv[2];
#pragma unroll
                for (int u = 0; u < 2; ++u) {
                    const size_t co = (size_t)(2 * k + u) << 12;
                    const uint_t u0 = q0[co], u1 = q1[co];
                    const float a0 = __uint_as_float(u0 << 16);
                    const float b0 = __uint_as_float(u0 & 0xffff0000u);
                    const float a1 = __uint_as_float(u1 << 16);
                    const float b1 = __uint_as_float(u1 & 0xffff0000u);
                    const float v = (a0 * wt.x + b0 * wt.y) * wt.z
                                  + (a1 * wt.x + b1 * wt.y) * wt.w;
                    sv[u] = f2bf(v);
                }
                o[k] = (uint_t)sv[0] | ((uint_t)sv[1] << 16);
            }
        } else {
            const float* p0 = xb + ((size_t)(cbase + ci0) << 12) + ii.x;
            const float* p1 = xb + ((size_t)(cbase + ci0) << 12) + ii.y;
#pragma unroll
            for (int k = 0; k < 4; ++k) {
                ushort_t sv[2];
#pragma unroll
                for (int u = 0; u < 2; ++u) {
                    const size_t co = (size_t)(2 * k + u) << 12;
                    const pairf a = *(const pairf*)(p0 + co);
                    const pairf c = *(const pairf*)(p1 + co);
                    const float v = (a.x * wt.x + a.y * wt.y) * wt.z
                                  + (c.x * wt.x + c.y * wt.y) * wt.w;
                    sv[u] = f2bf(v);
                }
                o[k] = (uint_t)sv[0] | ((uint_t)sv[1] << 16);
            }
        }
        *(uint4*)&As[bufi][px_s * 72 + ci0] = make_uint4(o[0], o[1], o[2], o[3]);
    };

    stage3(0, 0);
    __syncthreads();
    for (int q = 0; q < 36; ++q) {
        if (q < 35) stage3(q + 1, (q + 1) & 1);
        const short* cur = &As[q & 1][0];
#pragma unroll
        for (int k2 = 0; k2 < 2; ++k2) {
            const int ktg = q * 2 + k2;
            short8 a[4];
#pragma unroll
            for (int m = 0; m < 4; ++m)
                a[m] = *(const short8*)&cur[((m << 4) + (lane & 15)) * 72 + k2 * 32 + quad * 8];
            const ushort_t* wbp = wfrag + (((size_t)ktg * 16 + nt_base) * 64 + lane) * 8;
#pragma unroll
            for (int nn = 0; nn < 2; ++nn) {
                const short8 bf = *(const short8*)(wbp + nn * 512);
#pragma unroll
                for (int m = 0; m < 4; ++m)
                    acc[m][nn] = __builtin_amdgcn_mfma_f32_16x16x32_bf16(a[m], bf, acc[m][nn], 0, 0, 0);
            }
        }
        __syncthreads();
    }

    // epilogue: w = m*16 + quad*4 + reg; cout n = wv*32 + nn*16 + (lane&15)
#pragma unroll
    for (int m = 0; m < 4; ++m) {
        const int w = (m << 4) + (quad << 2);
#pragma unroll
        for (int nn = 0; nn < 2; ++nn) {
            const int n = (wv << 5) + (nn << 4) + (lane & 15);
            float* op = out + (((size_t)((b << 8) + n)) << 12) + (h << 6) + w;
            *(f32x4*)op = acc[m][nn];
        }
    }
}

extern "C" void kernel_launch(void* const* d_in, const int* in_sizes, int n_in,
                              void* d_out, int out_size, void* d_ws, size_t ws_size,
                              hipStream_t stream) {
    const float* x      = (const float*)d_in[0];
    const float* w_off  = (const float*)d_in[1];
    const float* b_off  = (const float*)d_in[2];
    const float* w_conv = (const float*)d_in[3];
    float* out = (float*)d_out;

    const size_t need = 4194304ull * 4 + 663552ull * 2;   // 18,104,320 B
    const bool use_pair = (ws_size >= need);

    uint_t*   xpair = (uint_t*)d_ws;
    ushort_t* wfrag = use_pair ? (ushort_t*)((char*)d_ws + 4194304ull * 4)
                               : (ushort_t*)d_ws;
    const int XB = use_pair ? 2048 : 0;

    hipLaunchKernelGGL(k_pre, dim3(XB + 2592), dim3(256), 0, stream,
                       x, w_conv, w_off, wfrag, xpair, XB);
    if (use_pair)
        hipLaunchKernelGGL((k_all<true>), dim3(256), dim3(512), 0, stream,
                           x, xpair, b_off, wfrag, out);
    else
        hipLaunchKernelGGL((k_all<false>), dim3(256), dim3(512), 0, stream,
                           x, nullptr, b_off, wfrag, out);
}

// Round 10
// 174.394 us; speedup vs baseline: 1.0213x; 1.0213x over previous
//
#include <hip/hip_runtime.h>

// Modulated deformable conv, fp32 in/out. B=4, CIN=COUT=256, H=W=64, KS=3, PAD=1.
// R10: xpair 4B gathers (R9) + 2 blocks/CU (R8). Block = 32 px x 256 couts,
// 512 thr, grid 512. Quarter-tap (64-cin) dbuf slabs, ~16 KB LDS.
// ws: [xpair: 4,194,304 uint = 16 MB][wfrag: 663,552 shorts = 1.33 MB] if it fits,
// else wfrag only (fp32 pairf-gather fallback).

#define WOFF_FRAG_OFF 589824
typedef unsigned short ushort_t;
typedef unsigned int   uint_t;

using short8 = __attribute__((ext_vector_type(8))) short;
using f32x4  = __attribute__((ext_vector_type(4))) float;

struct __attribute__((packed, aligned(4))) pairf { float x, y; };

__device__ inline ushort_t f2bf(float v) {
    unsigned u = __float_as_uint(v);
    unsigned r = u + 0x7fffu + ((u >> 16) & 1u);   // RNE (inputs finite)
    return (ushort_t)(r >> 16);
}

// ---- k_pre: [0, XB) blocks build xpair; [XB, XB+2592) scatter-swizzle weights ----
__global__ __launch_bounds__(256) void k_pre(
    const float* __restrict__ x,
    const float* __restrict__ w_conv,
    const float* __restrict__ w_off,
    ushort_t* __restrict__ wfrag,
    uint_t* __restrict__ xpair,
    int XB)
{
    const int bid = blockIdx.x;
    if (bid < XB) {
        const int gid = bid * 256 + threadIdx.x;
        const size_t base = (size_t)gid << 3;
        const float4 f0 = *(const float4*)(x + base);
        const float4 f1 = *(const float4*)(x + base + 4);
        const float nxt = (base + 8 < 4194304u) ? x[base + 8] : 0.f;
        const float e[9] = {f0.x, f0.y, f0.z, f0.w, f1.x, f1.y, f1.z, f1.w, nxt};
        uint_t o[8];
#pragma unroll
        for (int k = 0; k < 8; ++k)
            o[k] = (uint_t)f2bf(e[k]) | ((uint_t)f2bf(e[k + 1]) << 16);
        *(uint4*)(xpair + base)     = make_uint4(o[0], o[1], o[2], o[3]);
        *(uint4*)(xpair + base + 4) = make_uint4(o[4], o[5], o[6], o[7]);
        return;
    }
    const int i = (bid - XB) * 256 + threadIdx.x;   // 0..663,551
    if (i < 589824) {
        const int n = i / 2304;
        const int k_orig = i - n * 2304;
        const int cin = k_orig / 9;
        const int tap = k_orig - cin * 9;
        const int k_new = tap * 256 + cin;          // tap-outer
        const int kt = k_new >> 5, m = k_new & 31;
        const int lane = ((m >> 3) << 4) | (n & 15);
        wfrag[(((kt << 4) + (n >> 4)) * 64 + lane) * 8 + (m & 7)] = f2bf(w_conv[i]);
    } else if (i < 652032) {
        const int s = i - 589824;                    // w_off: 27 x 2304
        const int n = s / 2304;
        const int k_orig = s - n * 2304;
        const int cin = k_orig / 9;
        const int tap = k_orig - cin * 9;
        const int k_new = tap * 256 + cin;
        const int kt = k_new >> 5, m = k_new & 31;
        const int lane = ((m >> 3) << 4) | (n & 15);
        wfrag[WOFF_FRAG_OFF + ((kt * 2 + (n >> 4)) * 64 + lane) * 8 + (m & 7)] =
            f2bf(w_off[s]);
    } else {
        const int p = i - 652032;                    // zero-pad n=27..31
        const int kt = p / 160;
        const int rem = p - kt * 160;
        const int j = rem & 7, li = rem >> 3;
        const int g = li / 5, l = 11 + (li - g * 5);
        wfrag[WOFF_FRAG_OFF + ((kt * 2 + 1) * 64 + (g << 4) + l) * 8 + j] = 0;
    }
}

// ---- k_all: block = 32 px x 256 couts, 512 thr = 8 waves, grid 512 ----
template<bool USE_PAIR>
__global__ __launch_bounds__(512, 4) void k_all(
    const float* __restrict__ x,
    const uint_t* __restrict__ xpair,
    const float* __restrict__ b_off,
    const ushort_t* __restrict__ wfrag,
    float* __restrict__ out)
{
    __shared__ short As[2][32 * 72];                 // 9,216 B; px stride 72 shorts
    __shared__ __align__(16) float4 pwt[9 * 32];
    __shared__ __align__(16) int2   pidx[9 * 32];
    float* om_s = (float*)&As[0][0];                 // 32c x 32px fp32 = 4 KB alias

    const int bid = blockIdx.x;
    const int sid = ((bid & 7) << 6) | (bid >> 3);   // XCD-contiguous bands
    const int m0  = sid << 5;
    const int b   = m0 >> 12;
    const int h   = (m0 >> 6) & 63;
    const int wbase = m0 & 63;                        // 0 or 32
    const int tid  = threadIdx.x;
    const int lane = tid & 63;
    const int wv   = tid >> 6;                        // 0..7
    const int quad = lane >> 4;
    const int px   = tid & 31;                        // staging pixel
    const int slot = tid >> 5;                        // 0..15: 4 cins each

    const float*  xb = x + ((size_t)b << 20);
    const uint_t* xq = USE_PAIR ? xpair + ((size_t)b << 20) : nullptr;
    const ushort_t* woffb = wfrag + WOFF_FRAG_OFF;

    // ---------- phase 1: offset conv via MFMA, quarter-tap dbuf ----------
    const int m_w = wv & 1, nt_w = (wv >> 1) & 1;     // waves 0..3 cover 2m x 2nt
    f32x4 om_acc = {0.f, 0.f, 0.f, 0.f};

    auto stage1 = [&](int q, int bufi) {
        const int tap = q >> 2, cbase = (q & 3) << 6;
        const int ky = (tap * 11) >> 5, kx = tap - ky * 3;
        const int yy = h + ky - 1;
        const int xx = wbase + px + kx - 1;
        const bool v = ((unsigned)yy < 64u) & ((unsigned)xx < 64u);
        const int idx = v ? (yy << 6) + xx : 0;
        uint_t o[2];
        if (USE_PAIR) {
            const uint_t* p = xq + ((size_t)(cbase + (slot << 2)) << 12) + idx;
#pragma unroll
            for (int k = 0; k < 2; ++k) {
                const uint_t u0 = p[(size_t)(2 * k) << 12];
                const uint_t u1 = p[((size_t)(2 * k) + 1) << 12];
                const ushort_t s0 = v ? (ushort_t)(u0 & 0xffffu) : (ushort_t)0;
                const ushort_t s1 = v ? (ushort_t)(u1 & 0xffffu) : (ushort_t)0;
                o[k] = (uint_t)s0 | ((uint_t)s1 << 16);
            }
        } else {
            const float* p = xb + ((size_t)(cbase + (slot << 2)) << 12) + idx;
#pragma unroll
            for (int k = 0; k < 2; ++k) {
                float t0 = p[(size_t)(2 * k) << 12];
                float t1 = p[((size_t)(2 * k) + 1) << 12];
                t0 = v ? t0 : 0.f;  t1 = v ? t1 : 0.f;
                o[k] = (uint_t)f2bf(t0) | ((uint_t)f2bf(t1) << 16);
            }
        }
        *(uint2*)((uint_t*)&As[bufi][0] + px * 36 + slot * 2) = make_uint2(o[0], o[1]);
    };

    stage1(0, 0);
    __syncthreads();
    for (int q = 0; q < 36; ++q) {
        if (q < 35) stage1(q + 1, (q + 1) & 1);
        if (wv < 4) {
            const short* cur = &As[q & 1][0];
#pragma unroll
            for (int k2 = 0; k2 < 2; ++k2) {
                const int ktg = q * 2 + k2;
                const short8 a = *(const short8*)&cur[((m_w << 4) + (lane & 15)) * 72 + k2 * 32 + quad * 8];
                const short8 bf = *(const short8*)(woffb + ((size_t)(ktg * 2 + nt_w) * 64 + lane) * 8);
                om_acc = __builtin_amdgcn_mfma_f32_16x16x32_bf16(a, bf, om_acc, 0, 0, 0);
            }
        }
        __syncthreads();
    }
    if (wv < 4) {   // C/D: px = m_w*16 + quad*4 + reg; c = nt_w*16 + (lane&15)
        const int c = (nt_w << 4) + (lane & 15);
        *(f32x4*)&om_s[c * 32 + (m_w << 4) + (quad << 2)] = om_acc;
    }
    __syncthreads();

    // ---------- phase 2: per-(tap,px) pair-gather params ----------
    if (tid < 288) {
        const int p2 = tid & 31, tap = tid >> 5;
        const int ky = (tap * 11) >> 5, kx = tap - ky * 3;
        const float dyv = om_s[(2 * tap) * 32 + p2] + b_off[2 * tap];
        const float dxv = om_s[(2 * tap + 1) * 32 + p2] + b_off[2 * tap + 1];
        const float mo  = om_s[(18 + tap) * 32 + p2] + b_off[18 + tap];
        const float mv  = 1.f / (1.f + expf(-mo));
        const float py  = dyv + (float)(h - 1 + ky);
        const float pxf = dxv + (float)(wbase + p2 - 1 + kx);
        const float y0f = floorf(py), x0f = floorf(pxf);
        const float wy = py - y0f,    wx = pxf - x0f;
        const float vy0 = (y0f >=  0.f && y0f <= 63.f) ? 1.f : 0.f;
        const float vy1 = (y0f >= -1.f && y0f <= 62.f) ? 1.f : 0.f;
        const int ry0 = (int)fminf(fmaxf(y0f, 0.f), 63.f);
        const int ry1 = (int)fminf(fmaxf(y0f + 1.f, 0.f), 63.f);
        const float rw0 = (1.f - wy) * vy0 * mv;
        const float rw1 = wy * vy1 * mv;
        const bool in01 = (x0f >= 0.f && x0f <= 62.f);
        const float wa = in01 ? (1.f - wx) : ((x0f == -1.f) ? wx : 0.f);
        const float wb = in01 ? wx : ((x0f == 63.f) ? (1.f - wx) : 0.f);
        const int bx = (int)fminf(fmaxf(x0f, 0.f), 62.f);
        pwt[tid]  = make_float4(wa, wb, rw0, rw1);
        pidx[tid] = make_int2(ry0 * 64 + bx, ry1 * 64 + bx);
    }
    __syncthreads();

    // ---------- phase 3: deformable sampling + main GEMM ----------
    f32x4 acc[2][2];
#pragma unroll
    for (int m = 0; m < 2; ++m)
#pragma unroll
        for (int nn = 0; nn < 2; ++nn) acc[m][nn] = f32x4{0.f, 0.f, 0.f, 0.f};

    const int nt_base = wv << 1;                      // wave's couts: wv*32..+31

    auto stage3 = [&](int q, int bufi) {
        const int tap = q >> 2, cbase = (q & 3) << 6;
        const float4 wt = pwt[tap * 32 + px];
        const int2   ii = pidx[tap * 32 + px];
        uint_t o[2];
        if (USE_PAIR) {
            const uint_t* q0 = xq + ((size_t)(cbase + (slot << 2)) << 12) + ii.x;
            const uint_t* q1 = xq + ((size_t)(cbase + (slot << 2)) << 12) + ii.y;
#pragma unroll
            for (int k = 0; k < 2; ++k) {
                ushort_t sv[2];
#pragma unroll
                for (int u = 0; u < 2; ++u) {
                    const size_t co = (size_t)(2 * k + u) << 12;
                    const uint_t u0 = q0[co], u1 = q1[co];
                    const float a0 = __uint_as_float(u0 << 16);
                    const float b0 = __uint_as_float(u0 & 0xffff0000u);
                    const float a1 = __uint_as_float(u1 << 16);
                    const float b1 = __uint_as_float(u1 & 0xffff0000u);
                    const float v = (a0 * wt.x + b0 * wt.y) * wt.z
                                  + (a1 * wt.x + b1 * wt.y) * wt.w;
                    sv[u] = f2bf(v);
                }
                o[k] = (uint_t)sv[0] | ((uint_t)sv[1] << 16);
            }
        } else {
            const float* p0 = xb + ((size_t)(cbase + (slot << 2)) << 12) + ii.x;
            const float* p1 = xb + ((size_t)(cbase + (slot << 2)) << 12) + ii.y;
#pragma unroll
            for (int k = 0; k < 2; ++k) {
                ushort_t sv[2];
#pragma unroll
                for (int u = 0; u < 2; ++u) {
                    const size_t co = (size_t)(2 * k + u) << 12;
                    const pairf a = *(const pairf*)(p0 + co);
                    const pairf c = *(const pairf*)(p1 + co);
                    const float v = (a.x * wt.x + a.y * wt.y) * wt.z
                                  + (c.x * wt.x + c.y * wt.y) * wt.w;
                    sv[u] = f2bf(v);
                }
                o[k] = (uint_t)sv[0] | ((uint_t)sv[1] << 16);
            }
        }
        *(uint2*)((uint_t*)&As[bufi][0] + px * 36 + slot * 2) = make_uint2(o[0], o[1]);
    };

    stage3(0, 0);
    __syncthreads();
    for (int q = 0; q < 36; ++q) {
        if (q < 35) stage3(q + 1, (q + 1) & 1);
        const short* cur = &As[q & 1][0];
#pragma unroll
        for (int k2 = 0; k2 < 2; ++k2) {
            const int ktg = q * 2 + k2;
            short8 a[2];
#pragma unroll
            for (int m = 0; m < 2; ++m)
                a[m] = *(const short8*)&cur[((m << 4) + (lane & 15)) * 72 + k2 * 32 + quad * 8];
            const ushort_t* wbp = wfrag + (((size_t)ktg * 16 + nt_base) * 64 + lane) * 8;
#pragma unroll
            for (int nn = 0; nn < 2; ++nn) {
                const short8 bf = *(const short8*)(wbp + nn * 512);
#pragma unroll
                for (int m = 0; m < 2; ++m)
                    acc[m][nn] = __builtin_amdgcn_mfma_f32_16x16x32_bf16(a[m], bf, acc[m][nn], 0, 0, 0);
            }
        }
        __syncthreads();
    }

    // epilogue: w = wbase + m*16 + quad*4 + reg; cout n = wv*32 + nn*16 + (lane&15)
#pragma unroll
    for (int m = 0; m < 2; ++m) {
        const int w = wbase + (m << 4) + (quad << 2);
#pragma unroll
        for (int nn = 0; nn < 2; ++nn) {
            const int n = (wv << 5) + (nn << 4) + (lane & 15);
            float* op = out + (((size_t)((b << 8) + n)) << 12) + (h << 6) + w;
            *(f32x4*)op = acc[m][nn];
        }
    }
}

extern "C" void kernel_launch(void* const* d_in, const int* in_sizes, int n_in,
                              void* d_out, int out_size, void* d_ws, size_t ws_size,
                              hipStream_t stream) {
    const float* x      = (const float*)d_in[0];
    const float* w_off  = (const float*)d_in[1];
    const float* b_off  = (const float*)d_in[2];
    const float* w_conv = (const float*)d_in[3];
    float* out = (float*)d_out;

    const size_t need = 4194304ull * 4 + 663552ull * 2;   // 18,104,320 B
    const bool use_pair = (ws_size >= need);

    uint_t*   xpair = (uint_t*)d_ws;
    ushort_t* wfrag = use_pair ? (ushort_t*)((char*)d_ws + 4194304ull * 4)
                               : (ushort_t*)d_ws;
    const int XB = use_pair ? 2048 : 0;

    hipLaunchKernelGGL(k_pre, dim3(XB + 2592), dim3(256), 0, stream,
                       x, w_conv, w_off, wfrag, xpair, XB);
    if (use_pair)
        hipLaunchKernelGGL((k_all<true>), dim3(512), dim3(512), 0, stream,
                           x, xpair, b_off, wfrag, out);
    else
        hipLaunchKernelGGL((k_all<false>), dim3(512), dim3(512), 0, stream,
                           x, nullptr, b_off, wfrag, out);
}

// Round 11
// 171.504 us; speedup vs baseline: 1.0385x; 1.0168x over previous
//
#include <hip/hip_runtime.h>

// Modulated deformable conv, fp32 in/out. B=4, CIN=COUT=256, H=W=64, KS=3, PAD=1.
// R11: register-staged software pipeline: per slab write(LDS)->barrier->issue
// (gathers + B-frags into VGPRs)->MFMA; loads in flight across MFMA+barrier.
// 32-bit gather addressing (saddr+voffset). One barrier per slab (parity-safe).
// ws: [xpair 16 MB][wfrag 1.33 MB] if ws_size allows, else wfrag-only fallback.

#define WOFF_FRAG_OFF 589824
typedef unsigned short ushort_t;
typedef unsigned int   uint_t;

using short8 = __attribute__((ext_vector_type(8))) short;
using f32x4  = __attribute__((ext_vector_type(4))) float;

struct __attribute__((packed, aligned(4))) pairf { float x, y; };

__device__ inline ushort_t f2bf(float v) {
    unsigned u = __float_as_uint(v);
    unsigned r = u + 0x7fffu + ((u >> 16) & 1u);   // RNE (inputs finite)
    return (ushort_t)(r >> 16);
}
__device__ inline float bflo(uint_t u) { return __uint_as_float(u << 16); }
__device__ inline float bfhi(uint_t u) { return __uint_as_float(u & 0xffff0000u); }

// ---- k_pre: [0, XB) blocks build xpair; [XB, XB+2592) scatter-swizzle weights ----
__global__ __launch_bounds__(256) void k_pre(
    const float* __restrict__ x,
    const float* __restrict__ w_conv,
    const float* __restrict__ w_off,
    ushort_t* __restrict__ wfrag,
    uint_t* __restrict__ xpair,
    int XB)
{
    const int bid = blockIdx.x;
    if (bid < XB) {
        const int gid = bid * 256 + threadIdx.x;
        const size_t base = (size_t)gid << 3;
        const float4 f0 = *(const float4*)(x + base);
        const float4 f1 = *(const float4*)(x + base + 4);
        const float nxt = (base + 8 < 4194304u) ? x[base + 8] : 0.f;
        const float e[9] = {f0.x, f0.y, f0.z, f0.w, f1.x, f1.y, f1.z, f1.w, nxt};
        uint_t o[8];
#pragma unroll
        for (int k = 0; k < 8; ++k)
            o[k] = (uint_t)f2bf(e[k]) | ((uint_t)f2bf(e[k + 1]) << 16);
        *(uint4*)(xpair + base)     = make_uint4(o[0], o[1], o[2], o[3]);
        *(uint4*)(xpair + base + 4) = make_uint4(o[4], o[5], o[6], o[7]);
        return;
    }
    const int i = (bid - XB) * 256 + threadIdx.x;   // 0..663,551
    if (i < 589824) {
        const int n = i / 2304;
        const int k_orig = i - n * 2304;
        const int cin = k_orig / 9;
        const int tap = k_orig - cin * 9;
        const int k_new = tap * 256 + cin;          // tap-outer
        const int kt = k_new >> 5, m = k_new & 31;
        const int lane = ((m >> 3) << 4) | (n & 15);
        wfrag[(((kt << 4) + (n >> 4)) * 64 + lane) * 8 + (m & 7)] = f2bf(w_conv[i]);
    } else if (i < 652032) {
        const int s = i - 589824;                    // w_off: 27 x 2304
        const int n = s / 2304;
        const int k_orig = s - n * 2304;
        const int cin = k_orig / 9;
        const int tap = k_orig - cin * 9;
        const int k_new = tap * 256 + cin;
        const int kt = k_new >> 5, m = k_new & 31;
        const int lane = ((m >> 3) << 4) | (n & 15);
        wfrag[WOFF_FRAG_OFF + ((kt * 2 + (n >> 4)) * 64 + lane) * 8 + (m & 7)] =
            f2bf(w_off[s]);
    } else {
        const int p = i - 652032;                    // zero-pad n=27..31
        const int kt = p / 160;
        const int rem = p - kt * 160;
        const int j = rem & 7, li = rem >> 3;
        const int g = li / 5, l = 11 + (li - g * 5);
        wfrag[WOFF_FRAG_OFF + ((kt * 2 + 1) * 64 + (g << 4) + l) * 8 + j] = 0;
    }
}

// ---- k_all: block = 32 px x 256 couts, 512 thr = 8 waves, grid 512 ----
template<bool USE_PAIR>
__global__ __launch_bounds__(512, 4) void k_all(
    const float* __restrict__ x,
    const uint_t* __restrict__ xpair,
    const float* __restrict__ b_off,
    const ushort_t* __restrict__ wfrag,
    float* __restrict__ out)
{
    __shared__ short As[2][32 * 72];                 // 9,216 B; px stride 72 shorts
    __shared__ __align__(16) float4 pwt[9 * 32];
    __shared__ __align__(16) int2   pidx[9 * 32];
    float* om_s = (float*)&As[0][0];                 // 32c x 32px fp32 alias

    const int bid = blockIdx.x;
    const int sid = ((bid & 7) << 6) | (bid >> 3);   // XCD-contiguous bands
    const int m0  = sid << 5;
    const int b   = m0 >> 12;
    const int h   = (m0 >> 6) & 63;
    const int wbase = m0 & 63;                        // 0 or 32
    const int tid  = threadIdx.x;
    const int lane = tid & 63;
    const int wv   = tid >> 6;                        // 0..7
    const int quad = lane >> 4;
    const int px   = tid & 31;                        // staging pixel
    const int slot = tid >> 5;                        // 0..15: 4 cins each

    const float*  xb = x + (b << 20);
    const uint_t* xq = USE_PAIR ? xpair + (b << 20) : nullptr;
    const ushort_t* woffb = wfrag + WOFF_FRAG_OFF;

    // ================= phase 1: offset conv via MFMA, pipelined =================
    const int m_w = wv & 1, nt_w = (wv >> 1) & 1;     // waves 0..3 cover 2m x 2nt
    f32x4 om_acc = {0.f, 0.f, 0.f, 0.f};

    uint_t u1[2][4];
    float  f1[2][4];
    short8 w1[2][2];
    bool   vfl[2];

    auto issue1 = [&](int q, int pr) {
        const int tap = q >> 2, cbase = (q & 3) << 6;
        const int ky = (tap * 11) >> 5, kx = tap - ky * 3;
        const int yy = h + ky - 1;
        const int xx = wbase + px + kx - 1;
        const bool v = ((unsigned)yy < 64u) & ((unsigned)xx < 64u);
        vfl[pr] = v;
        const int idx = v ? (yy << 6) + xx : 0;
        const int cb = (cbase + (slot << 2)) << 12;
        if (USE_PAIR) {
#pragma unroll
            for (int k = 0; k < 4; ++k) u1[pr][k] = xq[cb + (k << 12) + idx];
        } else {
#pragma unroll
            for (int k = 0; k < 4; ++k) f1[pr][k] = xb[cb + (k << 12) + idx];
        }
        if (wv < 4) {
            const int ktg0 = q * 2;
            w1[pr][0] = *(const short8*)(woffb + ((ktg0 * 2 + nt_w) * 64 + lane) * 8);
            w1[pr][1] = *(const short8*)(woffb + (((ktg0 + 1) * 2 + nt_w) * 64 + lane) * 8);
        }
    };
    auto write1 = [&](int q, int pr) {
        uint_t o[2];
#pragma unroll
        for (int k = 0; k < 2; ++k) {
            ushort_t s0, s1;
            if (USE_PAIR) {
                s0 = vfl[pr] ? (ushort_t)(u1[pr][2 * k] & 0xffffu) : (ushort_t)0;
                s1 = vfl[pr] ? (ushort_t)(u1[pr][2 * k + 1] & 0xffffu) : (ushort_t)0;
            } else {
                s0 = f2bf(vfl[pr] ? f1[pr][2 * k] : 0.f);
                s1 = f2bf(vfl[pr] ? f1[pr][2 * k + 1] : 0.f);
            }
            o[k] = (uint_t)s0 | ((uint_t)s1 << 16);
        }
        *(uint2*)((uint_t*)&As[q & 1][0] + px * 36 + slot * 2) = make_uint2(o[0], o[1]);
    };
    auto mfma1 = [&](int q, int pr) {
        if (wv < 4) {
            const short* cur = &As[q & 1][0];
#pragma unroll
            for (int k2 = 0; k2 < 2; ++k2) {
                const short8 a = *(const short8*)&cur[((m_w << 4) + (lane & 15)) * 72 + k2 * 32 + quad * 8];
                om_acc = __builtin_amdgcn_mfma_f32_16x16x32_bf16(a, w1[pr][k2], om_acc, 0, 0, 0);
            }
        }
    };

    issue1(0, 0);
    for (int qq = 0; qq < 18; ++qq) {
        const int q0 = qq * 2, q1 = q0 + 1;
        write1(q0, 0);
        __syncthreads();
        issue1(q1, 1);
        mfma1(q0, 0);
        write1(q1, 1);
        __syncthreads();
        if (q1 < 35) issue1(q1 + 1, 0);
        mfma1(q1, 1);
    }
    if (wv < 4) {   // C/D: px = m_w*16 + quad*4 + reg; c = nt_w*16 + (lane&15)
        const int c = (nt_w << 4) + (lane & 15);
        *(f32x4*)&om_s[c * 32 + (m_w << 4) + (quad << 2)] = om_acc;
    }
    __syncthreads();

    // ================= phase 2: per-(tap,px) pair-gather params =================
    if (tid < 288) {
        const int p2 = tid & 31, tap = tid >> 5;
        const int ky = (tap * 11) >> 5, kx = tap - ky * 3;
        const float dyv = om_s[(2 * tap) * 32 + p2] + b_off[2 * tap];
        const float dxv = om_s[(2 * tap + 1) * 32 + p2] + b_off[2 * tap + 1];
        const float mo  = om_s[(18 + tap) * 32 + p2] + b_off[18 + tap];
        const float mv  = 1.f / (1.f + expf(-mo));
        const float py  = dyv + (float)(h - 1 + ky);
        const float pxf = dxv + (float)(wbase + p2 - 1 + kx);
        const float y0f = floorf(py), x0f = floorf(pxf);
        const float wy = py - y0f,    wx = pxf - x0f;
        const float vy0 = (y0f >=  0.f && y0f <= 63.f) ? 1.f : 0.f;
        const float vy1 = (y0f >= -1.f && y0f <= 62.f) ? 1.f : 0.f;
        const int ry0 = (int)fminf(fmaxf(y0f, 0.f), 63.f);
        const int ry1 = (int)fminf(fmaxf(y0f + 1.f, 0.f), 63.f);
        const float rw0 = (1.f - wy) * vy0 * mv;
        const float rw1 = wy * vy1 * mv;
        const bool in01 = (x0f >= 0.f && x0f <= 62.f);
        const float wa = in01 ? (1.f - wx) : ((x0f == -1.f) ? wx : 0.f);
        const float wb = in01 ? wx : ((x0f == 63.f) ? (1.f - wx) : 0.f);
        const int bx = (int)fminf(fmaxf(x0f, 0.f), 62.f);
        pwt[tid]  = make_float4(wa, wb, rw0, rw1);
        pidx[tid] = make_int2(ry0 * 64 + bx, ry1 * 64 + bx);
    }
    __syncthreads();

    // ================= phase 3: sampling + main GEMM, pipelined =================
    f32x4 acc[2][2];
#pragma unroll
    for (int m = 0; m < 2; ++m)
#pragma unroll
        for (int nn = 0; nn < 2; ++nn) acc[m][nn] = f32x4{0.f, 0.f, 0.f, 0.f};

    const int nt_base = wv << 1;                      // wave's couts: wv*32..+31

    uint_t g3[2][8];
    pairf  f3[2][8];
    short8 b3[2][4];
    float4 wt3[2];

    auto issue3 = [&](int q, int pr) {
        const int tap = q >> 2, cbase = (q & 3) << 6;
        wt3[pr] = pwt[tap * 32 + px];
        const int2 ii = pidx[tap * 32 + px];
        const int cb = (cbase + (slot << 2)) << 12;
        const int o0 = cb + ii.x, o1 = cb + ii.y;
        if (USE_PAIR) {
#pragma unroll
            for (int k = 0; k < 4; ++k) {
                g3[pr][k]     = xq[o0 + (k << 12)];
                g3[pr][4 + k] = xq[o1 + (k << 12)];
            }
        } else {
#pragma unroll
            for (int k = 0; k < 4; ++k) {
                f3[pr][k]     = *(const pairf*)(xb + o0 + (k << 12));
                f3[pr][4 + k] = *(const pairf*)(xb + o1 + (k << 12));
            }
        }
#pragma unroll
        for (int kk = 0; kk < 4; ++kk) {
            const int ktg = q * 2 + (kk >> 1);
            b3[pr][kk] = *(const short8*)(wfrag + ((ktg * 16 + nt_base + (kk & 1)) * 64 + lane) * 8);
        }
    };
    auto write3 = [&](int q, int pr) {
        const float4 wt = wt3[pr];
        uint_t o[2];
#pragma unroll
        for (int k = 0; k < 2; ++k) {
            float vv[2];
#pragma unroll
            for (int u = 0; u < 2; ++u) {
                const int c = 2 * k + u;
                float a0, b0, a1, b1;
                if (USE_PAIR) {
                    a0 = bflo(g3[pr][c]);     b0 = bfhi(g3[pr][c]);
                    a1 = bflo(g3[pr][4 + c]); b1 = bfhi(g3[pr][4 + c]);
                } else {
                    a0 = f3[pr][c].x;     b0 = f3[pr][c].y;
                    a1 = f3[pr][4 + c].x; b1 = f3[pr][4 + c].y;
                }
                vv[u] = (a0 * wt.x + b0 * wt.y) * wt.z + (a1 * wt.x + b1 * wt.y) * wt.w;
            }
            o[k] = (uint_t)f2bf(vv[0]) | ((uint_t)f2bf(vv[1]) << 16);
        }
        *(uint2*)((uint_t*)&As[q & 1][0] + px * 36 + slot * 2) = make_uint2(o[0], o[1]);
    };
    auto mfma3 = [&](int q, int pr) {
        const short* cur = &As[q & 1][0];
#pragma unroll
        for (int k2 = 0; k2 < 2; ++k2) {
            short8 a[2];
#pragma unroll
            for (int m = 0; m < 2; ++m)
                a[m] = *(const short8*)&cur[((m << 4) + (lane & 15)) * 72 + k2 * 32 + quad * 8];
#pragma unroll
            for (int nn = 0; nn < 2; ++nn)
#pragma unroll
                for (int m = 0; m < 2; ++m)
                    acc[m][nn] = __builtin_amdgcn_mfma_f32_16x16x32_bf16(a[m], b3[pr][k2 * 2 + nn], acc[m][nn], 0, 0, 0);
        }
    };

    issue3(0, 0);
    for (int qq = 0; qq < 18; ++qq) {
        const int q0 = qq * 2, q1 = q0 + 1;
        write3(q0, 0);
        __syncthreads();
        issue3(q1, 1);
        mfma3(q0, 0);
        write3(q1, 1);
        __syncthreads();
        if (q1 < 35) issue3(q1 + 1, 0);
        mfma3(q1, 1);
    }

    // epilogue: w = wbase + m*16 + quad*4 + reg; cout n = wv*32 + nn*16 + (lane&15)
#pragma unroll
    for (int m = 0; m < 2; ++m) {
        const int w = wbase + (m << 4) + (quad << 2);
#pragma unroll
        for (int nn = 0; nn < 2; ++nn) {
            const int n = (wv << 5) + (nn << 4) + (lane & 15);
            float* op = out + (((size_t)((b << 8) + n)) << 12) + (h << 6) + w;
            *(f32x4*)op = acc[m][nn];
        }
    }
}

extern "C" void kernel_launch(void* const* d_in, const int* in_sizes, int n_in,
                              void* d_out, int out_size, void* d_ws, size_t ws_size,
                              hipStream_t stream) {
    const float* x      = (const float*)d_in[0];
    const float* w_off  = (const float*)d_in[1];
    const float* b_off  = (const float*)d_in[2];
    const float* w_conv = (const float*)d_in[3];
    float* out = (float*)d_out;

    const size_t need = 4194304ull * 4 + 663552ull * 2;   // 18,104,320 B
    const bool use_pair = (ws_size >= need);

    uint_t*   xpair = (uint_t*)d_ws;
    ushort_t* wfrag = use_pair ? (ushort_t*)((char*)d_ws + 4194304ull * 4)
                               : (ushort_t*)d_ws;
    const int XB = use_pair ? 2048 : 0;

    hipLaunchKernelGGL(k_pre, dim3(XB + 2592), dim3(256), 0, stream,
                       x, w_conv, w_off, wfrag, xpair, XB);
    if (use_pair)
        hipLaunchKernelGGL((k_all<true>), dim3(512), dim3(512), 0, stream,
                           x, xpair, b_off, wfrag, out);
    else
        hipLaunchKernelGGL((k_all<false>), dim3(512), dim3(512), 0, stream,
                           x, nullptr, b_off, wfrag, out);
}

// Round 12
// 167.198 us; speedup vs baseline: 1.0653x; 1.0258x over previous
//
#include <hip/hip_runtime.h>

// Modulated deformable conv, fp32 in/out. B=4, CIN=COUT=256, H=W=64, KS=3, PAD=1.
// R12: transposed xpair (xqT[b][idx][cin], bf16-pair per uint) -> 16B gather loads
// (4x fewer addresses); k_pre rebuilt: LDS-transpose xpairT + gather-read/
// coalesced-store wfrag; full-tap slabs (9 per phase, barriers 72->20).
// ws: [xpairT 16 MB][wfrag 1.33 MB]; fallback to direct-fp32 path if ws too small.

#define WOFF_FRAG_OFF 589824
typedef unsigned short ushort_t;
typedef unsigned int   uint_t;

using short8 = __attribute__((ext_vector_type(8))) short;
using f32x4  = __attribute__((ext_vector_type(4))) float;

struct __attribute__((packed, aligned(4))) pairf { float x, y; };

__device__ inline ushort_t f2bf(float v) {
    unsigned u = __float_as_uint(v);
    unsigned r = u + 0x7fffu + ((u >> 16) & 1u);   // RNE (inputs finite)
    return (ushort_t)(r >> 16);
}
__device__ inline float bflo(uint_t u) { return __uint_as_float(u << 16); }
__device__ inline float bfhi(uint_t u) { return __uint_as_float(u & 0xffff0000u); }

// k_pre: blocks [0,XB): xpairT tile-transpose; [XB,XB+288): w_conv frags;
// [XB+288,XB+324): w_off frags. All global stores coalesced 16B.
__global__ __launch_bounds__(256) void k_pre(
    const float* __restrict__ x,
    const float* __restrict__ w_conv,
    const float* __restrict__ w_off,
    ushort_t* __restrict__ wfrag,
    uint_t* __restrict__ xpair,
    int XB)
{
    __shared__ uint_t tl[32 * 258];                  // 33 KB transpose tile
    const int bid = blockIdx.x;
    const int t = threadIdx.x;
    if (bid < XB) {
        // xqT[((b*4096 + idx)*256) + cin] = (bf16 x[b][cin][idx], bf16 x[b][cin][idx+1])
        const int b = bid >> 7;
        const int idx0 = (bid & 127) << 5;           // 32 idx rows per block
        const int idx_l = t & 31;
        const int cgrp = t >> 5;                     // 0..7 -> 32 cins each
        const float* xb = x + (b << 20);
        const int gidx = idx0 + idx_l;
        const bool has_hi = (gidx & 63) < 63;        // hi unused when gx==63
        for (int c2 = 0; c2 < 32; ++c2) {
            const int cin = (cgrp << 5) + c2;
            const float lo = xb[(cin << 12) + gidx];
            const float hi = has_hi ? xb[(cin << 12) + gidx + 1] : 0.f;
            tl[idx_l * 258 + cin] = (uint_t)f2bf(lo) | ((uint_t)f2bf(hi) << 16);
        }
        __syncthreads();
        uint_t* op = xpair + (((b << 12) + idx0) << 8);
        for (int r = 0; r < 8; ++r) {
            const int l = r * 256 + t;
            const int il = l >> 6, c4 = (l & 63) << 2;
            *(uint4*)(op + (il << 8) + c4) = *(const uint4*)&tl[il * 258 + c4];
        }
        return;
    }
    const int wb = bid - XB;
    if (wb < 288) {                                   // w_conv fragment rows
        const int i8 = wb * 256 + t;                  // 0..73727
        const int lane = i8 & 63;
        const int nt = (i8 >> 6) & 15;
        const int kt = i8 >> 10;                      // 0..71
        const int n = nt * 16 + (lane & 15);
        const int k0 = kt * 32 + ((lane >> 4) << 3);
        ushort_t v[8];
#pragma unroll
        for (int j = 0; j < 8; ++j) {
            const int kn = k0 + j;                    // tap-outer: kn = tap*256+cin
            const int cin = kn & 255, tap = kn >> 8;
            v[j] = f2bf(w_conv[n * 2304 + cin * 9 + tap]);
        }
        uint4 o;
        o.x = (uint_t)v[0] | ((uint_t)v[1] << 16);
        o.y = (uint_t)v[2] | ((uint_t)v[3] << 16);
        o.z = (uint_t)v[4] | ((uint_t)v[5] << 16);
        o.w = (uint_t)v[6] | ((uint_t)v[7] << 16);
        *(uint4*)(wfrag + (size_t)i8 * 8) = o;
    } else {                                          // w_off fragment rows (+pad)
        const int i8 = (wb - 288) * 256 + t;          // 0..9215
        const int lane = i8 & 63;
        const int nt = (i8 >> 6) & 1;
        const int kt = i8 >> 7;                       // 0..71
        const int n = nt * 16 + (lane & 15);
        const int k0 = kt * 32 + ((lane >> 4) << 3);
        ushort_t v[8];
#pragma unroll
        for (int j = 0; j < 8; ++j) {
            const int kn = k0 + j;
            const int cin = kn & 255, tap = kn >> 8;
            v[j] = (n < 27) ? f2bf(w_off[n * 2304 + cin * 9 + tap]) : (ushort_t)0;
        }
        uint4 o;
        o.x = (uint_t)v[0] | ((uint_t)v[1] << 16);
        o.y = (uint_t)v[2] | ((uint_t)v[3] << 16);
        o.z = (uint_t)v[4] | ((uint_t)v[5] << 16);
        o.w = (uint_t)v[6] | ((uint_t)v[7] << 16);
        *(uint4*)(wfrag + WOFF_FRAG_OFF + (size_t)i8 * 8) = o;
    }
}

// ---- k_all: block = 32 px x 256 couts, 512 thr = 8 waves, grid 512 ----
template<bool USE_PAIR>
__global__ __launch_bounds__(512, 4) void k_all(
    const float* __restrict__ x,
    const uint_t* __restrict__ xpair,
    const float* __restrict__ b_off,
    const ushort_t* __restrict__ wfrag,
    float* __restrict__ out)
{
    __shared__ short As[2][32 * 264];                // 33,792 B; px stride 264 shorts
    __shared__ __align__(16) float4 pwt[9 * 32];
    __shared__ __align__(16) int2   pidx[9 * 32];
    float* om_s = (float*)&As[0][0];                 // 32c x 32px fp32 alias

    const int bid = blockIdx.x;
    const int sid = ((bid & 7) << 6) | (bid >> 3);   // XCD-contiguous bands
    const int m0  = sid << 5;
    const int b   = m0 >> 12;
    const int h   = (m0 >> 6) & 63;
    const int wbase = m0 & 63;                        // 0 or 32
    const int tid  = threadIdx.x;
    const int lane = tid & 63;
    const int wv   = tid >> 6;                        // 0..7
    const int quad = lane >> 4;
    const int px   = tid & 31;                        // staging pixel
    const int slot = tid >> 5;                        // 0..15: 16 cins each

    const float*  xb = x + (b << 20);
    const uint_t* xq = xpair + (b << 20);
    const ushort_t* woffb = wfrag + WOFF_FRAG_OFF;

    // ================= phase 1: offset conv via MFMA, full-tap slabs ============
    const int m_w = wv & 1, nt_w = (wv >> 1) & 1;     // waves 0..3 cover 2m x 2nt
    f32x4 om_acc = {0.f, 0.f, 0.f, 0.f};

    auto stage1 = [&](int tap, int bufi) {
        const int ky = (tap * 11) >> 5, kx = tap - ky * 3;
        const int yy = h + ky - 1;
        const int xx = wbase + px + kx - 1;
        const bool v = ((unsigned)yy < 64u) & ((unsigned)xx < 64u);
        const int idx = v ? (yy << 6) + xx : 0;
        uint_t lo16[16];
        if (USE_PAIR) {
            const uint_t* p = xq + (idx << 8) + (slot << 4);
            uint4 r[4];
#pragma unroll
            for (int g = 0; g < 4; ++g) r[g] = *(const uint4*)(p + g * 4);
            const uint_t* rr = (const uint_t*)r;
#pragma unroll
            for (int c = 0; c < 16; ++c) lo16[c] = v ? (rr[c] & 0xffffu) : 0u;
        } else {
#pragma unroll
            for (int c = 0; c < 16; ++c) {
                const int cin = (slot << 4) + c;
                const float t0 = xb[(cin << 12) + idx];
                lo16[c] = v ? (uint_t)f2bf(t0) : 0u;
            }
        }
        uint_t o[8];
#pragma unroll
        for (int k = 0; k < 8; ++k) o[k] = lo16[2 * k] | (lo16[2 * k + 1] << 16);
        uint_t* dst = (uint_t*)&As[bufi][0] + px * 132 + slot * 8;
        *(uint4*)dst       = make_uint4(o[0], o[1], o[2], o[3]);
        *(uint4*)(dst + 4) = make_uint4(o[4], o[5], o[6], o[7]);
    };
    auto mfma1 = [&](int tap) {
        if (wv < 4) {
            const short* cur = &As[tap & 1][0];
#pragma unroll
            for (int k2 = 0; k2 < 8; ++k2) {
                const int ktg = tap * 8 + k2;
                const short8 a = *(const short8*)&cur[((m_w << 4) + (lane & 15)) * 264 + k2 * 32 + quad * 8];
                const short8 bf = *(const short8*)(woffb + ((ktg * 2 + nt_w) * 64 + lane) * 8);
                om_acc = __builtin_amdgcn_mfma_f32_16x16x32_bf16(a, bf, om_acc, 0, 0, 0);
            }
        }
    };

    stage1(0, 0);
    __syncthreads();
    for (int tap = 0; tap < 9; ++tap) {
        if (tap < 8) stage1(tap + 1, (tap + 1) & 1);
        mfma1(tap);
        __syncthreads();
    }
    if (wv < 4) {   // C/D: px = m_w*16 + quad*4 + reg; c = nt_w*16 + (lane&15)
        const int c = (nt_w << 4) + (lane & 15);
        *(f32x4*)&om_s[c * 32 + (m_w << 4) + (quad << 2)] = om_acc;
    }
    __syncthreads();

    // ================= phase 2: per-(tap,px) pair-gather params =================
    if (tid < 288) {
        const int p2 = tid & 31, tap = tid >> 5;
        const int ky = (tap * 11) >> 5, kx = tap - ky * 3;
        const float dyv = om_s[(2 * tap) * 32 + p2] + b_off[2 * tap];
        const float dxv = om_s[(2 * tap + 1) * 32 + p2] + b_off[2 * tap + 1];
        const float mo  = om_s[(18 + tap) * 32 + p2] + b_off[18 + tap];
        const float mv  = 1.f / (1.f + expf(-mo));
        const float py  = dyv + (float)(h - 1 + ky);
        const float pxf = dxv + (float)(wbase + p2 - 1 + kx);
        const float y0f = floorf(py), x0f = floorf(pxf);
        const float wy = py - y0f,    wx = pxf - x0f;
        const float vy0 = (y0f >=  0.f && y0f <= 63.f) ? 1.f : 0.f;
        const float vy1 = (y0f >= -1.f && y0f <= 62.f) ? 1.f : 0.f;
        const int ry0 = (int)fminf(fmaxf(y0f, 0.f), 63.f);
        const int ry1 = (int)fminf(fmaxf(y0f + 1.f, 0.f), 63.f);
        const float rw0 = (1.f - wy) * vy0 * mv;
        const float rw1 = wy * vy1 * mv;
        const bool in01 = (x0f >= 0.f && x0f <= 62.f);
        const float wa = in01 ? (1.f - wx) : ((x0f == -1.f) ? wx : 0.f);
        const float wb = in01 ? wx : ((x0f == 63.f) ? (1.f - wx) : 0.f);
        const int bx = (int)fminf(fmaxf(x0f, 0.f), 62.f);
        pwt[tid]  = make_float4(wa, wb, rw0, rw1);
        pidx[tid] = make_int2(ry0 * 64 + bx, ry1 * 64 + bx);
    }
    __syncthreads();

    // ================= phase 3: sampling + main GEMM, full-tap slabs ============
    f32x4 acc[2][2];
#pragma unroll
    for (int m = 0; m < 2; ++m)
#pragma unroll
        for (int nn = 0; nn < 2; ++nn) acc[m][nn] = f32x4{0.f, 0.f, 0.f, 0.f};

    const int nt_base = wv << 1;                      // wave's couts: wv*32..+31

    auto stage3 = [&](int tap, int bufi) {
        const float4 wt = pwt[tap * 32 + px];
        const int2   ii = pidx[tap * 32 + px];
        uint_t o[8];
        if (USE_PAIR) {
            const uint_t* p0 = xq + (ii.x << 8) + (slot << 4);
            const uint_t* p1 = xq + (ii.y << 8) + (slot << 4);
            uint4 r0[4], r1[4];
#pragma unroll
            for (int g = 0; g < 4; ++g) {
                r0[g] = *(const uint4*)(p0 + g * 4);
                r1[g] = *(const uint4*)(p1 + g * 4);
            }
            const uint_t* a0 = (const uint_t*)r0;
            const uint_t* a1 = (const uint_t*)r1;
#pragma unroll
            for (int k = 0; k < 8; ++k) {
                ushort_t s[2];
#pragma unroll
                for (int u = 0; u < 2; ++u) {
                    const int c = 2 * k + u;
                    const float v = (bflo(a0[c]) * wt.x + bfhi(a0[c]) * wt.y) * wt.z
                                  + (bflo(a1[c]) * wt.x + bfhi(a1[c]) * wt.y) * wt.w;
                    s[u] = f2bf(v);
                }
                o[k] = (uint_t)s[0] | ((uint_t)s[1] << 16);
            }
        } else {
#pragma unroll
            for (int k = 0; k < 8; ++k) {
                ushort_t s[2];
#pragma unroll
                for (int u = 0; u < 2; ++u) {
                    const int cin = (slot << 4) + 2 * k + u;
                    const pairf pa = *(const pairf*)(xb + (cin << 12) + ii.x);
                    const pairf pb = *(const pairf*)(xb + (cin << 12) + ii.y);
                    const float v = (pa.x * wt.x + pa.y * wt.y) * wt.z
                                  + (pb.x * wt.x + pb.y * wt.y) * wt.w;
                    s[u] = f2bf(v);
                }
                o[k] = (uint_t)s[0] | ((uint_t)s[1] << 16);
            }
        }
        uint_t* dst = (uint_t*)&As[bufi][0] + px * 132 + slot * 8;
        *(uint4*)dst       = make_uint4(o[0], o[1], o[2], o[3]);
        *(uint4*)(dst + 4) = make_uint4(o[4], o[5], o[6], o[7]);
    };
    auto mfma3 = [&](int tap) {
        const short* cur = &As[tap & 1][0];
#pragma unroll
        for (int k2 = 0; k2 < 8; ++k2) {
            const int ktg = tap * 8 + k2;
            short8 a[2];
            a[0] = *(const short8*)&cur[(lane & 15) * 264 + k2 * 32 + quad * 8];
            a[1] = *(const short8*)&cur[((lane & 15) + 16) * 264 + k2 * 32 + quad * 8];
#pragma unroll
            for (int nn = 0; nn < 2; ++nn) {
                const short8 bf = *(const short8*)(wfrag + ((ktg * 16 + nt_base + nn) * 64 + lane) * 8);
                acc[0][nn] = __builtin_amdgcn_mfma_f32_16x16x32_bf16(a[0], bf, acc[0][nn], 0, 0, 0);
                acc[1][nn] = __builtin_amdgcn_mfma_f32_16x16x32_bf16(a[1], bf, acc[1][nn], 0, 0, 0);
            }
        }
    };

    stage3(0, 0);
    __syncthreads();
    for (int tap = 0; tap < 9; ++tap) {
        if (tap < 8) stage3(tap + 1, (tap + 1) & 1);
        mfma3(tap);
        __syncthreads();
    }

    // epilogue: w = wbase + m*16 + quad*4 + reg; cout n = wv*32 + nn*16 + (lane&15)
#pragma unroll
    for (int m = 0; m < 2; ++m) {
        const int w = wbase + (m << 4) + (quad << 2);
#pragma unroll
        for (int nn = 0; nn < 2; ++nn) {
            const int n = (wv << 5) + (nn << 4) + (lane & 15);
            float* op = out + (((size_t)((b << 8) + n)) << 12) + (h << 6) + w;
            *(f32x4*)op = acc[m][nn];
        }
    }
}

extern "C" void kernel_launch(void* const* d_in, const int* in_sizes, int n_in,
                              void* d_out, int out_size, void* d_ws, size_t ws_size,
                              hipStream_t stream) {
    const float* x      = (const float*)d_in[0];
    const float* w_off  = (const float*)d_in[1];
    const float* b_off  = (const float*)d_in[2];
    const float* w_conv = (const float*)d_in[3];
    float* out = (float*)d_out;

    const size_t need = 4194304ull * 4 + 663552ull * 2;   // 18,104,320 B
    const bool use_pair = (ws_size >= need);

    uint_t*   xpair = (uint_t*)d_ws;
    ushort_t* wfrag = use_pair ? (ushort_t*)((char*)d_ws + 4194304ull * 4)
                               : (ushort_t*)d_ws;
    const int XB = use_pair ? 512 : 0;

    hipLaunchKernelGGL(k_pre, dim3(XB + 324), dim3(256), 0, stream,
                       x, w_conv, w_off, wfrag, xpair, XB);
    if (use_pair)
        hipLaunchKernelGGL((k_all<true>), dim3(512), dim3(512), 0, stream,
                           x, xpair, b_off, wfrag, out);
    else
        hipLaunchKernelGGL((k_all<false>), dim3(512), dim3(512), 0, stream,
                           x, xpair, b_off, wfrag, out);
}